// Round 9
// baseline (44.396 us; speedup 1.0000x reference)
//
#include <hip/hip_runtime.h>
#include <stdint.h>

#define NEGV (-1e30f)

constexpr int L1_ = 512;
constexpr int H_  = 128;
constexpr int NK_ = 2048;   // 32 turns * 64 tokens

typedef __attribute__((ext_vector_type(8))) _Float16 f16x8;
typedef __attribute__((ext_vector_type(2))) __fp16   h16x2;
typedef __attribute__((ext_vector_type(4))) float    f32x4;

static __device__ __forceinline__ uint16_t f2h(float x) {
    union { _Float16 h; uint16_t u; } cv; cv.h = (_Float16)x; return cv.u;
}

// Fragment-major layouts (16B chunk per lane, lane = (g<<4)|n16):
//  Y2[kt(32)][kkT(4)][ks(4)][lane]  chunk = yp[kt*64+kkT*16+n16][ks*32+g*8 .. +8]
//  V2[kt(32)][cT(8)][ks(2)][lane]   chunk = dlg[kt*64+ks*32+g*8+j][cT*16+n16]
//  W2[cT(8)][ks(4)][lane]           chunk = W [cT*16+n16][ks*32+g*8 .. +8]

// ---------------------------------------------------------------------------
// Preprocessing, 256 threads/block (unchanged from R8):
//  [0,128):   yproj 16 rows -> Y2
//  [128,160): dlg turn -> V2
//  160:       masks -> badd
//  161:       W -> W2
// ---------------------------------------------------------------------------
__global__ __launch_bounds__(256) void preproc_kernel(
        const float* __restrict__ xq,
        const float* __restrict__ xa,
        const float* __restrict__ W,
        const float* __restrict__ bias,
        const uint8_t* __restrict__ qm,
        const uint8_t* __restrict__ am,
        uint8_t* __restrict__ Y2,
        uint8_t* __restrict__ V2,
        uint8_t* __restrict__ W2,
        float* __restrict__ badd) {
    int b = blockIdx.x;
    int tid = threadIdx.x;
    __shared__ __align__(16) float sbuf[64 * 128];   // 32 KB

    if (b < 128) {
        int k0 = b * 16;
        f32x4* xr4 = (f32x4*)sbuf;
#pragma unroll
        for (int i = 0; i < 2; ++i) {
            int idx = tid + i * 256;
            int row = idx >> 5, d4 = idx & 31;
            int k = k0 + row;
            int b2 = k >> 6, r = k & 63;
            const float* src = (r < 32) ? (xq + (size_t)(b2 * 32 + r) * H_)
                                        : (xa + (size_t)(b2 * 32 + (r - 32)) * H_);
            xr4[idx] = *(const f32x4*)(src + d4 * 4);
        }
        __syncthreads();
        int c = tid & 127, rh = tid >> 7;
        float acc[8];
#pragma unroll
        for (int i = 0; i < 8; ++i) acc[i] = 0.0f;
        const f32x4* w4 = (const f32x4*)(W + (size_t)c * H_);
        for (int d4 = 0; d4 < 32; ++d4) {
            f32x4 wv = w4[d4];
#pragma unroll
            for (int i = 0; i < 8; ++i) {
                f32x4 x = xr4[(rh * 8 + i) * 32 + d4];
                acc[i] += wv[0]*x[0] + wv[1]*x[1] + wv[2]*x[2] + wv[3]*x[3];
            }
        }
        float bc = bias[c];
        float* res = sbuf + 2048;
#pragma unroll
        for (int i = 0; i < 8; ++i)
            res[(rh * 8 + i) * H_ + c] = fmaxf(acc[i] + bc, 0.0f);
        __syncthreads();
        int ks = tid >> 6, l = tid & 63, n16 = l & 15, g = l >> 4;
        uint16_t hbuf[8];
#pragma unroll
        for (int j = 0; j < 8; ++j)
            hbuf[j] = f2h(res[n16 * H_ + ks * 32 + g * 8 + j]);
        uint8_t* dst = Y2 + (((size_t)b * 4 + ks) << 10) + l * 16;
        *(uint64_t*)dst       = ((const uint64_t*)hbuf)[0];
        *(uint64_t*)(dst + 8) = ((const uint64_t*)hbuf)[1];
    } else if (b < 160) {
        int kt = b - 128;
        f32x4* ld4 = (f32x4*)sbuf;
#pragma unroll
        for (int i = 0; i < 8; ++i) {
            int idx = tid + i * 256;
            int row = idx >> 5, d4 = idx & 31;
            const float* src = (row < 32) ? (xq + (size_t)(kt * 32 + row) * H_)
                                          : (xa + (size_t)(kt * 32 + row - 32) * H_);
            ld4[idx] = *(const f32x4*)(src + d4 * 4);
        }
        __syncthreads();
#pragma unroll
        for (int i = 0; i < 4; ++i) {
            int id = tid + i * 256;
            int cT = id >> 7, ks = (id >> 6) & 1, l = id & 63;
            int n16 = l & 15, g = l >> 4;
            uint16_t hbuf[8];
#pragma unroll
            for (int j = 0; j < 8; ++j)
                hbuf[j] = f2h(sbuf[(ks * 32 + g * 8 + j) * H_ + cT * 16 + n16]);
            uint8_t* dst = V2 + (((size_t)kt * 16 + cT * 2 + ks) << 10) + l * 16;
            *(uint64_t*)dst       = ((const uint64_t*)hbuf)[0];
            *(uint64_t*)(dst + 8) = ((const uint64_t*)hbuf)[1];
        }
    } else if (b == 160) {
        int* flags = (int*)sbuf;
        if (tid == 0) { flags[0] = 0; flags[1] = 0; }
        __syncthreads();
        uint32_t v = ((const uint32_t*)qm)[tid] | ((const uint32_t*)am)[tid];
        if (v & 0xFFu)        atomicOr(&flags[0], 1);
        if (v & 0xFFFFFF00u)  atomicOr(&flags[1], 1);
        __syncthreads();
        int f0 = flags[0], f1 = flags[1];
        int mode = (f0 && !f1) ? 0 : ((!f0 && f1) ? 1 : 2);
        for (int k = tid; k < NK_; k += 256) {
            int b2 = k >> 6, r = k & 63;
            int idx = b2 * 32 + (r < 32 ? r : r - 32);
            const uint8_t* src = (r < 32) ? qm : am;
            int p;
            if (mode == 0)      p = (((const int*)src)[idx] != 0);
            else if (mode == 1) p = (((const float*)src)[idx] != 0.0f);
            else                p = (src[idx] != 0);
            badd[k] = p ? NEGV : 0.0f;
        }
    } else {
        for (int h = 0; h < 2; ++h) {
            f32x4* s4 = (f32x4*)sbuf;
#pragma unroll
            for (int i = 0; i < 8; ++i) {
                int idx = tid + i * 256;
                s4[idx] = *(const f32x4*)(W + (size_t)h * 64 * H_ + idx * 4);
            }
            __syncthreads();
#pragma unroll
            for (int i = 0; i < 4; ++i) {
                int id = tid + i * 256;
                int ct = id >> 8, ks = (id >> 6) & 3, l = id & 63;
                int n16 = l & 15, g = l >> 4;
                uint16_t hb[8];
#pragma unroll
                for (int j = 0; j < 8; ++j)
                    hb[j] = f2h(sbuf[(ct * 16 + n16) * H_ + ks * 32 + g * 8 + j]);
                uint8_t* dst = W2 + (((size_t)((h * 4 + ct) * 4 + ks)) << 10) + l * 16;
                *(uint64_t*)dst       = ((const uint64_t*)hb)[0];
                *(uint64_t*)(dst + 8) = ((const uint64_t*)hb)[1];
            }
            __syncthreads();
        }
    }
}

// ---------------------------------------------------------------------------
// Flash attention: 512 threads / 8 waves per block, 32 l-rows, k-stride 8.
// Fused x-projection prologue; fenced batch loads; 2-pass epilogue combine.
// ---------------------------------------------------------------------------
__global__ __launch_bounds__(512, 2) void attn_kernel(
        const float*   __restrict__ xd,
        const uint8_t* __restrict__ W2,
        const float*   __restrict__ bias,
        const uint8_t* __restrict__ Y2,
        const uint8_t* __restrict__ V2,
        const float*   __restrict__ badd,
        const float*   __restrict__ rw,
        float* __restrict__ out) {
    int bid = blockIdx.x;
    int t, lt;
    if (bid < 256) { int p = bid >> 4; t = (p < 15) ? 31 - p : 16; lt = bid & 15; }
    else           { int b2 = bid - 256; int p = b2 >> 4; t = (p < 15) ? p + 1 : 0; lt = b2 & 15; }
    int l0 = lt << 5;
    int tid = threadIdx.x;

    __shared__ __align__(16) float smem[16384];        // 64 KB: P (32 KB) / epilogue
    __shared__ float stats_m[8][32];
    __shared__ float stats_l[8][32];

    if (t == 0) {                  // zero_first
        f32x4 z = {0.f, 0.f, 0.f, 0.f};
        f32x4* o4 = (f32x4*)(out + (size_t)l0 * H_);
        for (int i = tid; i < 32 * H_ / 4; i += 512) o4[i] = z;
        return;
    }

    int w = tid >> 6, lane = tid & 63, n16 = lane & 15, g = lane >> 4;
    int prow0 = n16, prow1 = 16 + n16;
    int swzP = (n16 & 7) << 4;

    // ================= x-projection prologue (MFMA) =================
    uint16_t* xbuf  = (uint16_t*)((char*)smem + 32768);   // [32][128] fp16 swz
    uint16_t* xpbuf = (uint16_t*)((char*)smem + 40960);   // [32][128] fp16 swz
    {
        const float* xsrc = xd + (size_t)(t * L1_ + l0) * H_;
#pragma unroll
        for (int i = 0; i < 2; ++i) {
            int idx = tid + i * 512;          // 1024 f32x4
            int row = idx >> 5, c4 = idx & 31;
            f32x4 v = *(const f32x4*)(xsrc + idx * 4);
            uint16_t hb[4] = { f2h(v[0]), f2h(v[1]), f2h(v[2]), f2h(v[3]) };
            *(uint64_t*)((char*)xbuf + row * 256 + ((c4 * 8) ^ ((row & 7) << 4)))
                = *(const uint64_t*)hb;
        }
    }
    __syncthreads();
    {
        f16x8 af[2][4];
#pragma unroll
        for (int rT = 0; rT < 2; ++rT) {
            int row = rT * 16 + n16, swz = (row & 7) << 4;
#pragma unroll
            for (int ks = 0; ks < 4; ++ks)
                af[rT][ks] = *(const f16x8*)((char*)xbuf + row * 256 + ((ks * 64 + g * 16) ^ swz));
        }
        f32x4 z4 = {0.f, 0.f, 0.f, 0.f};
        f32x4 d0 = z4, d1 = z4;               // wave w owns cT = w
#pragma unroll
        for (int ks = 0; ks < 4; ++ks) {
            f16x8 wf = *(const f16x8*)(W2 + (((size_t)w * 4 + ks) << 10) + lane * 16);
            d0 = __builtin_amdgcn_mfma_f32_16x16x32_f16(af[0][ks], wf, d0, 0, 0, 0);
            d1 = __builtin_amdgcn_mfma_f32_16x16x32_f16(af[1][ks], wf, d1, 0, 0, 0);
        }
        float bb = bias[w * 16 + n16];
#pragma unroll
        for (int rT = 0; rT < 2; ++rT) {
            const f32x4& d = rT ? d1 : d0;
#pragma unroll
            for (int q = 0; q < 4; ++q) {
                int row = rT * 16 + g * 4 + q, swz = (row & 7) << 4;
                *(uint16_t*)((char*)xpbuf + row * 256 + (((w * 16 + n16) * 2) ^ swz))
                    = f2h(fmaxf(d[q] + bb, 0.0f));
            }
        }
    }
    __syncthreads();
    f16x8 xf[2][4];
#pragma unroll
    for (int rT = 0; rT < 2; ++rT) {
        int row = rT * 16 + n16, swz = (row & 7) << 4;
#pragma unroll
        for (int ks = 0; ks < 4; ++ks)
            xf[rT][ks] = *(const f16x8*)((char*)xpbuf + row * 256 + ((ks * 64 + g * 16) ^ swz));
    }

    // ================= main loop (k-stride 8, per-wave independent) =========
    f32x4 zero4 = {0.f, 0.f, 0.f, 0.f};
    f32x4 acc[2][8];
#pragma unroll
    for (int a = 0; a < 2; ++a)
#pragma unroll
        for (int c = 0; c < 8; ++c) acc[a][c] = zero4;

    float m_r[2] = {-INFINITY, -INFINITY};
    float l_r[2] = {0.0f, 0.0f};
    float rww = rw[0];

    char* Pw = (char*)smem + w * 4096;     // per-wave 4 KB P buffer (8 waves = 32 KB)

    for (int kt = w; kt < t; kt += 8) {
        const uint8_t* ybase = Y2 + ((size_t)kt << 14) + lane * 16;
        const uint8_t* vbase = V2 + ((size_t)kt << 14) + lane * 16;

        // ---- batch-issue: 16 y + 8 vA + 4 badd loads, FENCE
        f16x8 yf[4][4];
#pragma unroll
        for (int kkT = 0; kkT < 4; ++kkT)
#pragma unroll
            for (int ks = 0; ks < 4; ++ks)
                yf[kkT][ks] = *(const f16x8*)(ybase + ((kkT * 4 + ks) << 10));
        f16x8 vbA[4][2];
#pragma unroll
        for (int cT = 0; cT < 4; ++cT) {
            vbA[cT][0] = *(const f16x8*)(vbase + ((cT * 2) << 10));
            vbA[cT][1] = *(const f16x8*)(vbase + ((cT * 2 + 1) << 10));
        }
        f32x4 ba4[4];
#pragma unroll
        for (int kkT = 0; kkT < 4; ++kkT)
            ba4[kkT] = *(const f32x4*)(badd + kt * 64 + kkT * 16 + g * 4);
        __builtin_amdgcn_sched_barrier(0);

        // ---- S^T: 32 MFMAs
        f32x4 ss[4][2];
#pragma unroll
        for (int kkT = 0; kkT < 4; ++kkT) { ss[kkT][0] = zero4; ss[kkT][1] = zero4; }
#pragma unroll
        for (int ks = 0; ks < 4; ++ks)
#pragma unroll
            for (int kkT = 0; kkT < 4; ++kkT) {
                ss[kkT][0] = __builtin_amdgcn_mfma_f32_16x16x32_f16(yf[kkT][ks], xf[0][ks], ss[kkT][0], 0, 0, 0);
                ss[kkT][1] = __builtin_amdgcn_mfma_f32_16x16x32_f16(yf[kkT][ks], xf[1][ks], ss[kkT][1], 0, 0, 0);
            }

        // ---- batch-issue second-half v loads, FENCE (land under softmax)
        f16x8 vbB[4][2];
#pragma unroll
        for (int cT = 0; cT < 4; ++cT) {
            vbB[cT][0] = *(const f16x8*)(vbase + (((cT + 4) * 2) << 10));
            vbB[cT][1] = *(const f16x8*)(vbase + (((cT + 4) * 2 + 1) << 10));
        }
        __builtin_amdgcn_sched_barrier(0);

        // ---- mask + recency bias
        float biasK = rww * (float)(t - kt);
#pragma unroll
        for (int kkT = 0; kkT < 4; ++kkT) {
            f32x4 ba = ba4[kkT] + biasK;
            ss[kkT][0] += ba;
            ss[kkT][1] += ba;
        }

        // ---- per-row online max
        float sc[2];
#pragma unroll
        for (int rT = 0; rT < 2; ++rT) {
            f32x4 mx4 = ss[0][rT];
#pragma unroll
            for (int kkT = 1; kkT < 4; ++kkT) {
                mx4[0] = fmaxf(mx4[0], ss[kkT][rT][0]);
                mx4[1] = fmaxf(mx4[1], ss[kkT][rT][1]);
                mx4[2] = fmaxf(mx4[2], ss[kkT][rT][2]);
                mx4[3] = fmaxf(mx4[3], ss[kkT][rT][3]);
            }
            float mx = fmaxf(fmaxf(mx4[0], mx4[1]), fmaxf(mx4[2], mx4[3]));
            mx = fmaxf(mx, __shfl_xor(mx, 16));
            mx = fmaxf(mx, __shfl_xor(mx, 32));
            float mn = fmaxf(m_r[rT], mx);
            sc[rT] = __expf(m_r[rT] - mn);
            m_r[rT] = mn;
        }

        // ---- P = exp(s - m), partial sums, write P to wave-local LDS
#pragma unroll
        for (int rT = 0; rT < 2; ++rT) {
            int r = rT ? prow1 : prow0;
            float mn = m_r[rT];
            float ps = 0.0f;
#pragma unroll
            for (int kkT = 0; kkT < 4; ++kkT) {
                f32x4 p;
#pragma unroll
                for (int q = 0; q < 4; ++q) p[q] = __expf(ss[kkT][rT][q] - mn);
                ps += (p[0] + p[1]) + (p[2] + p[3]);
                union { h16x2 h2[2]; uint64_t u64; } pk;
                pk.h2[0] = __builtin_amdgcn_cvt_pkrtz(p[0], p[1]);
                pk.h2[1] = __builtin_amdgcn_cvt_pkrtz(p[2], p[3]);
                *(uint64_t*)(Pw + r * 128 + ((kkT * 32 + g * 8) ^ swzP)) = pk.u64;
            }
            ps += __shfl_xor(ps, 16);
            ps += __shfl_xor(ps, 32);
            l_r[rT] = l_r[rT] * sc[rT] + ps;
        }

        asm volatile("s_waitcnt lgkmcnt(0)" ::: "memory");

        // ---- rescale O accumulator (skip when max didn't move)
        if (!__all((sc[0] == 1.0f) && (sc[1] == 1.0f))) {
#pragma unroll
            for (int rT = 0; rT < 2; ++rT) {
                f32x4 s4;
#pragma unroll
                for (int q = 0; q < 4; ++q) s4[q] = __shfl(sc[rT], (g << 2) + q);
#pragma unroll
                for (int cT = 0; cT < 8; ++cT) acc[rT][cT] *= s4;
            }
        }

        // ---- PV: 32 MFMAs
        f16x8 pa[2][2];
#pragma unroll
        for (int rT = 0; rT < 2; ++rT) {
            int r = rT ? prow1 : prow0;
#pragma unroll
            for (int ks = 0; ks < 2; ++ks)
                pa[rT][ks] = *(const f16x8*)(Pw + r * 128 + ((ks * 64 + g * 16) ^ swzP));
        }
#pragma unroll
        for (int cT = 0; cT < 4; ++cT)
#pragma unroll
            for (int rT = 0; rT < 2; ++rT) {
                acc[rT][cT] = __builtin_amdgcn_mfma_f32_16x16x32_f16(pa[rT][0], vbA[cT][0], acc[rT][cT], 0, 0, 0);
                acc[rT][cT] = __builtin_amdgcn_mfma_f32_16x16x32_f16(pa[rT][1], vbA[cT][1], acc[rT][cT], 0, 0, 0);
            }
#pragma unroll
        for (int cT = 0; cT < 4; ++cT)
#pragma unroll
            for (int rT = 0; rT < 2; ++rT) {
                acc[rT][cT + 4] = __builtin_amdgcn_mfma_f32_16x16x32_f16(pa[rT][0], vbB[cT][0], acc[rT][cT + 4], 0, 0, 0);
                acc[rT][cT + 4] = __builtin_amdgcn_mfma_f32_16x16x32_f16(pa[rT][1], vbB[cT][1], acc[rT][cT + 4], 0, 0, 0);
            }
    }

    // ---- cross-wave combine (8 waves), 2-pass epilogue
    if (g == 0) {
        stats_m[w][n16]      = m_r[0];
        stats_m[w][16 + n16] = m_r[1];
        stats_l[w][n16]      = l_r[0];
        stats_l[w][16 + n16] = l_r[1];
    }
    __syncthreads();

    float fac[2][4];
#pragma unroll
    for (int rT = 0; rT < 2; ++rT)
#pragma unroll
        for (int q = 0; q < 4; ++q) {
            int r = rT * 16 + (g << 2) + q;
            float mf = stats_m[0][r];
#pragma unroll
            for (int wv = 1; wv < 8; ++wv) mf = fmaxf(mf, stats_m[wv][r]);
            float lf = 0.0f;
#pragma unroll
            for (int wv = 0; wv < 8; ++wv) lf += stats_l[wv][r] * __expf(stats_m[wv][r] - mf);
            fac[rT][q] = __expf(stats_m[w][r] - mf) / lf;
        }

    size_t obase = (size_t)(t * L1_ + l0) * H_;
    for (int rT = 0; rT < 2; ++rT) {
        float* Ob = smem + w * 2048;       // 32 slots x 64 lanes per wave
#pragma unroll
        for (int cT = 0; cT < 8; ++cT)
#pragma unroll
            for (int q = 0; q < 4; ++q)
                Ob[(cT * 4 + q) * 64 + lane] = acc[rT][cT][q] * fac[rT][q];
        __syncthreads();
#pragma unroll
        for (int s = 0; s < 4; ++s) {
            int slot = w * 4 + s;
            float v = 0.0f;
#pragma unroll
            for (int wv = 0; wv < 8; ++wv) v += smem[wv * 2048 + slot * 64 + lane];
            int cT = slot >> 2, q = slot & 3;
            out[obase + (size_t)(rT * 16 + (g << 2) + q) * H_ + cT * 16 + n16] = v;
        }
        __syncthreads();
    }
}

// ---------------------------------------------------------------------------
extern "C" void kernel_launch(void* const* d_in, const int* in_sizes, int n_in,
                              void* d_out, int out_size, void* d_ws, size_t ws_size,
                              hipStream_t stream) {
    const float*   xd   = (const float*)d_in[0];
    const float*   xq   = (const float*)d_in[1];
    const float*   xa   = (const float*)d_in[2];
    const float*   W    = (const float*)d_in[3];
    const float*   bias = (const float*)d_in[4];
    const float*   rw   = (const float*)d_in[5];
    const uint8_t* qm   = (const uint8_t*)d_in[6];
    const uint8_t* am   = (const uint8_t*)d_in[7];
    float* out = (float*)d_out;

    char* ws = (char*)d_ws;
    float*   badd = (float*)ws;                          // 8 KB
    uint8_t* Y2   = (uint8_t*)(ws + 8192);               // 512 KB
    uint8_t* V2   = (uint8_t*)(ws + 8192 + 524288);      // 512 KB
    uint8_t* W2   = (uint8_t*)(ws + 8192 + 2 * 524288);  // 32 KB

    preproc_kernel<<<162, 256, 0, stream>>>(xq, xa, W, bias, qm, am,
                                            Y2, V2, W2, badd);
    attn_kernel<<<512, 512, 0, stream>>>(xd, W2, bias, Y2, V2, badd, rw, out);
}